// Round 9
// baseline (617.950 us; speedup 1.0000x reference)
//
#include <hip/hip_runtime.h>
#include <math.h>

// Net: 4 layers of out = 0.8*(x@W^T) + 0.2*max_i(W[o,i]*x[b,i]) + b
// B=1024, dims 256 -> 512 -> 512 -> 512 -> 1. All fp32.
//
// R9: fix the LDS-broadcast wall. R5-R8 had every wave re-reading all 4 rows
// of h (4096 ds_read_b128/CU/layer ~ 51us of LDS pipe -- the measured wall).
// New decomposition: wave w owns row (w&3) and o-half (w>>2); lane owns 4
// consecutive o's. h reads per CU drop 4x -> LDS pipe ~12.3k cyc/layer,
// balanced with VALU. W streamed as A/B ping-pong (4-k4 groups, no copy
// movs, compile-time indices only -- R6 scratch lesson). W panels are
// pre-transposed coalesced [k4][o] float4 in d_ws.

#define NT   512
#define ROWS 4

typedef float v4f __attribute__((ext_vector_type(4)));

// ws layout in float4 units
#define WT1_OFF 0
#define WT2_OFF 33280    // 32768 + 512 pad
#define WT3_OFF 99328    // 33280 + 65536 + 512 pad

__global__ __launch_bounds__(256) void transpose_all(
    const float* __restrict__ W1, const float* __restrict__ W2,
    const float* __restrict__ W3, float4* __restrict__ ws)
{
    const int tid = blockIdx.x * 256 + threadIdx.x;   // 0 .. 163839
    const float* W;
    float4* WT;
    int o, k4, K;
    if (tid < 32768) {                    // W1: O=512, K=256, K4=64
        W = W1; WT = ws + WT1_OFF; K = 256;
        o = tid >> 6; k4 = tid & 63;
    } else if (tid < 98304) {             // W2: O=512, K=512, K4=128
        const int idx = tid - 32768;
        W = W2; WT = ws + WT2_OFF; K = 512;
        o = idx >> 7; k4 = idx & 127;
    } else {                              // W3: O=512, K=512, K4=128
        const int idx = tid - 98304;
        W = W3; WT = ws + WT3_OFF; K = 512;
        o = idx >> 7; k4 = idx & 127;
    }
    float4 v = *(const float4*)&W[(size_t)o * K + 4 * k4];
    WT[(size_t)k4 * 512 + o] = v;
}

// One 4-k4 group of compute for 1 row x 4 o's.
#define COMPUTE_GRP(Wset, Hset)                                             \
    {                                                                       \
        _Pragma("unroll")                                                   \
        for (int j = 0; j < 4; ++j) {                                       \
            const v4f h = Hset[j];                                          \
            _Pragma("unroll")                                               \
            for (int o = 0; o < 4; ++o) {                                   \
                v4f p = Wset[j][o] * h;                                     \
                s4[o] += p;                                                 \
                mA[o] = fmaxf(fmaxf(mA[o], p[0]), p[1]);                    \
                mB[o] = fmaxf(fmaxf(mB[o], p[2]), p[3]);                    \
            }                                                               \
        }                                                                   \
    }

#define LOAD_GRP(Wset, Hset, KBASE)                                         \
    {                                                                       \
        _Pragma("unroll")                                                   \
        for (int j = 0; j < 4; ++j) {                                       \
            _Pragma("unroll")                                               \
            for (int o = 0; o < 4; ++o)                                     \
                Wset[j][o] = wp[(size_t)((KBASE) + j) * 512 + o];           \
            Hset[j] = *(const v4f*)&hin[row][4 * ((KBASE) + j)];            \
        }                                                                   \
    }

// Wave-sliced layer: this thread computes Y[row][obase..obase+3].
template<int K4>
__device__ __forceinline__ void layer_wave(
    const float (*__restrict__ hin)[512],
    float (*__restrict__ hout)[512],
    const v4f* __restrict__ WT,      // [K4][512] coalesced panels
    const float* __restrict__ bias,
    int row, int obase)
{
    v4f s4[4];
    float mA[4], mB[4];
    #pragma unroll
    for (int o = 0; o < 4; ++o) {
        s4[o] = (v4f)0.f;
        mA[o] = -INFINITY;
        mB[o] = -INFINITY;
    }

    const v4f* wp = WT + obase;

    v4f A[4][4], B[4][4], hA[4], hB[4];
    LOAD_GRP(A, hA, 0);
    LOAD_GRP(B, hB, 4);

    #pragma unroll 1
    for (int kg = 0; kg < K4; kg += 8) {
        // phase A: compute group kg; refill A with group kg+8
        COMPUTE_GRP(A, hA);
        if (kg + 8 < K4) LOAD_GRP(A, hA, kg + 8);
        // phase B: compute group kg+4; refill B with group kg+12
        COMPUTE_GRP(B, hB);
        if (kg + 12 < K4) LOAD_GRP(B, hB, kg + 12);
    }

    const v4f bv = *(const v4f*)&bias[obase];
    v4f y;
    #pragma unroll
    for (int o = 0; o < 4; ++o) {
        float s = (s4[o][0] + s4[o][1]) + (s4[o][2] + s4[o][3]);
        float m = fmaxf(mA[o], mB[o]);
        y[o] = fmaf(0.2f, m, fmaf(0.8f, s, bv[o]));
    }
    *(v4f*)&hout[row][obase] = y;
}

__global__ __launch_bounds__(NT, 1) void net_fused(
    const float* __restrict__ x,
    const v4f* __restrict__ WT1, const float* __restrict__ b1,
    const v4f* __restrict__ WT2, const float* __restrict__ b2,
    const v4f* __restrict__ WT3, const float* __restrict__ b3,
    const float* __restrict__ W4, const float* __restrict__ b4,
    float* __restrict__ out)
{
    __shared__ __align__(16) float ha[ROWS][512];
    __shared__ __align__(16) float hb[ROWS][512];
    __shared__ float red_s[8][ROWS];
    __shared__ float red_m[8][ROWS];

    const int t = threadIdx.x;
    const int row0 = blockIdx.x * ROWS;

    // stage x rows (4 x 256) into ha: one float2 per thread
    {
        const int r = t >> 7;
        const int c = (t & 127) * 2;
        float2 v = *(const float2*)&x[(size_t)(row0 + r) * 256 + c];
        ha[r][c]     = v.x;
        ha[r][c + 1] = v.y;
    }
    __syncthreads();

    const int wave  = t >> 6;
    const int lane  = t & 63;
    const int row   = wave & 3;                    // this wave's batch row
    const int obase = (wave >> 2) * 256 + lane * 4; // 4 consecutive o's

    layer_wave<64> (ha, hb, WT1, b1, row, obase);   // x  -> h1
    __syncthreads();
    layer_wave<128>(hb, ha, WT2, b2, row, obase);   // h1 -> h2
    __syncthreads();
    layer_wave<128>(ha, hb, WT3, b3, row, obase);   // h2 -> h3
    __syncthreads();

    // ---- layer 4: O=1 ----
    const float w4 = W4[t];
    float ps[ROWS], pm[ROWS];
    #pragma unroll
    for (int r = 0; r < ROWS; ++r) {
        float p = w4 * hb[r][t];
        ps[r] = p;
        pm[r] = p;
    }
    #pragma unroll
    for (int off = 32; off; off >>= 1) {
        #pragma unroll
        for (int r = 0; r < ROWS; ++r) {
            ps[r] += __shfl_xor(ps[r], off, 64);
            pm[r] = fmaxf(pm[r], __shfl_xor(pm[r], off, 64));
        }
    }
    if (lane == 0) {
        #pragma unroll
        for (int r = 0; r < ROWS; ++r) {
            red_s[wave][r] = ps[r];
            red_m[wave][r] = pm[r];
        }
    }
    __syncthreads();

    if (t < ROWS) {
        float s = red_s[0][t];
        float m = red_m[0][t];
        #pragma unroll
        for (int w = 1; w < 8; ++w) {
            s += red_s[w][t];
            m = fmaxf(m, red_m[w][t]);
        }
        out[row0 + t] = fmaf(0.2f, m, fmaf(0.8f, s, b4[0]));
    }
}

extern "C" void kernel_launch(void* const* d_in, const int* in_sizes, int n_in,
                              void* d_out, int out_size, void* d_ws, size_t ws_size,
                              hipStream_t stream)
{
    const float* x  = (const float*)d_in[0];
    const float* W1 = (const float*)d_in[1];
    const float* b1 = (const float*)d_in[2];
    const float* W2 = (const float*)d_in[3];
    const float* b2 = (const float*)d_in[4];
    const float* W3 = (const float*)d_in[5];
    const float* b3 = (const float*)d_in[6];
    const float* W4 = (const float*)d_in[7];
    const float* b4 = (const float*)d_in[8];

    float4* ws4 = (float4*)d_ws;

    transpose_all<<<640, 256, 0, stream>>>(W1, W2, W3, ws4);

    net_fused<<<256, NT, 0, stream>>>(
        x,
        (const v4f*)(ws4 + WT1_OFF), b1,
        (const v4f*)(ws4 + WT2_OFF), b2,
        (const v4f*)(ws4 + WT3_OFF), b3,
        W4, b4,
        (float*)d_out);
}

// Round 10
// 117.619 us; speedup vs baseline: 5.2538x; 5.2538x over previous
//
#include <hip/hip_runtime.h>
#include <math.h>

// Net: 4 layers of out = 0.8*(x@W^T) + 0.2*max_i(W[o,i]*x[b,i]) + b
// B=1024, dims 256 -> 512 -> 512 -> 512 -> 1. All fp32.
//
// R10: kill the LDS pipe entirely. R7's wall was 10240 broadcast
// ds_read_b128/CU ~ 51us on the per-CU LDS pipe. h reads are wave-uniform,
// so move them to the SCALAR pipe: per-layer kernels where h is a const
// __restrict__ input (uniform address + no-clobber -> s_load_dwordx4),
// consumed directly as the SGPR operand of v_pk_mul_f32. W streams from
// pre-transposed coalesced [k4][o] panels into VGPRs. No ds_read, no LDS.
// All registers NAMED (R6/R9 spill lessons): ~60 VGPR, ~90 SGPR.

#define NT   512
#define ROWS 4

typedef float v2f __attribute__((ext_vector_type(2)));
typedef float v4f __attribute__((ext_vector_type(4)));

#define V2LO(v) __builtin_shufflevector((v), (v), 0, 1)
#define V2HI(v) __builtin_shufflevector((v), (v), 2, 3)

// d_ws layout in float4 units
#define WT1_OFF 0
#define WT2_OFF 33280    // 32768 + 512 pad
#define WT3_OFF 99328    // 33280 + 65536 + 512 pad
#define H_OFF   164864   // h buffers (float4 units): h1, h2, h3 (128K f4 each)

__global__ __launch_bounds__(256) void transpose_all(
    const float* __restrict__ W1, const float* __restrict__ W2,
    const float* __restrict__ W3, float4* __restrict__ ws)
{
    const int tid = blockIdx.x * 256 + threadIdx.x;   // 0 .. 163839
    const float* W;
    float4* WT;
    int o, k4, K;
    if (tid < 32768) {                    // W1: O=512, K=256, K4=64
        W = W1; WT = ws + WT1_OFF; K = 256;
        o = tid >> 6; k4 = tid & 63;
    } else if (tid < 98304) {             // W2: O=512, K=512, K4=128
        const int idx = tid - 32768;
        W = W2; WT = ws + WT2_OFF; K = 512;
        o = idx >> 7; k4 = idx & 127;
    } else {                              // W3: O=512, K=512, K4=128
        const int idx = tid - 98304;
        W = W3; WT = ws + WT3_OFF; K = 512;
        o = idx >> 7; k4 = idx & 127;
    }
    float4 v = *(const float4*)&W[(size_t)o * K + 4 * k4];
    WT[(size_t)k4 * 512 + o] = v;
}

// one k4 (4 k-elems) for all 4 rows; w in VGPR, H* expected in SGPRs.
#define K4_STEP(wv, H0, H1, H2, H3)                                         \
    {                                                                       \
        const v2f wLo = V2LO(wv), wHi = V2HI(wv);                           \
        { v2f pL = V2LO(H0) * wLo, pH = V2HI(H0) * wHi;                     \
          sL0 += pL; sH0 += pH;                                             \
          mL0 = fmaxf(fmaxf(mL0, pL[0]), pL[1]);                            \
          mH0 = fmaxf(fmaxf(mH0, pH[0]), pH[1]); }                          \
        { v2f pL = V2LO(H1) * wLo, pH = V2HI(H1) * wHi;                     \
          sL1 += pL; sH1 += pH;                                             \
          mL1 = fmaxf(fmaxf(mL1, pL[0]), pL[1]);                            \
          mH1 = fmaxf(fmaxf(mH1, pH[0]), pH[1]); }                          \
        { v2f pL = V2LO(H2) * wLo, pH = V2HI(H2) * wHi;                     \
          sL2 += pL; sH2 += pH;                                             \
          mL2 = fmaxf(fmaxf(mL2, pL[0]), pL[1]);                            \
          mH2 = fmaxf(fmaxf(mH2, pH[0]), pH[1]); }                          \
        { v2f pL = V2LO(H3) * wLo, pH = V2HI(H3) * wHi;                     \
          sL3 += pL; sH3 += pH;                                             \
          mL3 = fmaxf(fmaxf(mL3, pL[0]), pL[1]);                            \
          mH3 = fmaxf(fmaxf(mH3, pH[0]), pH[1]); }                          \
    }

// Per-layer kernel: thread t owns output neuron o=t; block owns 4 batch rows.
// X: h-input (uniform scalar loads). WT: coalesced [K4][512] panels.
template<int K>
__global__ __launch_bounds__(NT) void layer_k(
    const float* __restrict__ X,     // B x K
    const v4f*  __restrict__ WT,     // [K/4][512]
    const float* __restrict__ bias,  // 512
    float* __restrict__ Y)           // B x 512
{
    constexpr int K4 = K / 4;
    const int t = threadIdx.x;
    const int row0 = blockIdx.x * ROWS;

    const v4f* xr0 = (const v4f*)(X + (size_t)(row0 + 0) * K);
    const v4f* xr1 = (const v4f*)(X + (size_t)(row0 + 1) * K);
    const v4f* xr2 = (const v4f*)(X + (size_t)(row0 + 2) * K);
    const v4f* xr3 = (const v4f*)(X + (size_t)(row0 + 3) * K);

    v2f sL0 = (v2f)0.f, sH0 = (v2f)0.f, sL1 = (v2f)0.f, sH1 = (v2f)0.f;
    v2f sL2 = (v2f)0.f, sH2 = (v2f)0.f, sL3 = (v2f)0.f, sH3 = (v2f)0.f;
    float mL0 = -INFINITY, mH0 = -INFINITY, mL1 = -INFINITY, mH1 = -INFINITY;
    float mL2 = -INFINITY, mH2 = -INFINITY, mL3 = -INFINITY, mH3 = -INFINITY;

    const v4f* wp = WT + t;

    // preload stages A (k4=0,1) and B (k4=2,3)
    v4f wA0 = wp[0],    wA1 = wp[512];
    v4f wB0 = wp[1024], wB1 = wp[1536];
    v4f hA00 = xr0[0], hA01 = xr1[0], hA02 = xr2[0], hA03 = xr3[0];
    v4f hA10 = xr0[1], hA11 = xr1[1], hA12 = xr2[1], hA13 = xr3[1];
    v4f hB00 = xr0[2], hB01 = xr1[2], hB02 = xr2[2], hB03 = xr3[2];
    v4f hB10 = xr0[3], hB11 = xr1[3], hB12 = xr2[3], hB13 = xr3[3];

    #pragma unroll 1
    for (int kg = 0; kg < K4; kg += 4) {
        // ---- stage A: compute k4 = kg, kg+1; refill from kg+4, kg+5 ----
        K4_STEP(wA0, hA00, hA01, hA02, hA03);
        K4_STEP(wA1, hA10, hA11, hA12, hA13);
        if (kg + 4 < K4) {                      // uniform branch
            wA0 = wp[(size_t)(kg + 4) * 512];
            wA1 = wp[(size_t)(kg + 5) * 512];
            hA00 = xr0[kg + 4]; hA01 = xr1[kg + 4];
            hA02 = xr2[kg + 4]; hA03 = xr3[kg + 4];
            hA10 = xr0[kg + 5]; hA11 = xr1[kg + 5];
            hA12 = xr2[kg + 5]; hA13 = xr3[kg + 5];
        }
        // ---- stage B: compute k4 = kg+2, kg+3; refill from kg+6, kg+7 ----
        K4_STEP(wB0, hB00, hB01, hB02, hB03);
        K4_STEP(wB1, hB10, hB11, hB12, hB13);
        if (kg + 6 < K4) {
            wB0 = wp[(size_t)(kg + 6) * 512];
            wB1 = wp[(size_t)(kg + 7) * 512];
            hB00 = xr0[kg + 6]; hB01 = xr1[kg + 6];
            hB02 = xr2[kg + 6]; hB03 = xr3[kg + 6];
            hB10 = xr0[kg + 7]; hB11 = xr1[kg + 7];
            hB12 = xr2[kg + 7]; hB13 = xr3[kg + 7];
        }
    }

    const float bo = bias[t];
    {
        v2f sv = sL0 + sH0;
        Y[(size_t)(row0 + 0) * 512 + t] =
            fmaf(0.2f, fmaxf(mL0, mH0), fmaf(0.8f, sv[0] + sv[1], bo));
    }
    {
        v2f sv = sL1 + sH1;
        Y[(size_t)(row0 + 1) * 512 + t] =
            fmaf(0.2f, fmaxf(mL1, mH1), fmaf(0.8f, sv[0] + sv[1], bo));
    }
    {
        v2f sv = sL2 + sH2;
        Y[(size_t)(row0 + 2) * 512 + t] =
            fmaf(0.2f, fmaxf(mL2, mH2), fmaf(0.8f, sv[0] + sv[1], bo));
    }
    {
        v2f sv = sL3 + sH3;
        Y[(size_t)(row0 + 3) * 512 + t] =
            fmaf(0.2f, fmaxf(mL3, mH3), fmaf(0.8f, sv[0] + sv[1], bo));
    }
}

// Final layer: O=1. One wave per batch row, wave shuffle reduction.
__global__ __launch_bounds__(256) void layer4_kernel(
    const float* __restrict__ H,    // 1024 x 512
    const float* __restrict__ W4,   // 512
    const float* __restrict__ b4,   // 1
    float* __restrict__ out)        // 1024
{
    const int wave = threadIdx.x >> 6;
    const int lane = threadIdx.x & 63;
    const int b = blockIdx.x * 4 + wave;

    const float* h = H + (size_t)b * 512;

    float s = 0.f;
    float m = -INFINITY;
    #pragma unroll
    for (int i = 0; i < 2; ++i) {
        const int k = i * 256 + lane * 4;
        float4 hv = *(const float4*)&h[k];
        float4 wv = *(const float4*)&W4[k];
        float p0 = hv.x * wv.x;
        float p1 = hv.y * wv.y;
        float p2 = hv.z * wv.z;
        float p3 = hv.w * wv.w;
        s += p0 + p1 + p2 + p3;
        m = fmaxf(m, fmaxf(fmaxf(p0, p1), fmaxf(p2, p3)));
    }

    #pragma unroll
    for (int off = 32; off; off >>= 1) {
        s += __shfl_xor(s, off, 64);
        m = fmaxf(m, __shfl_xor(m, off, 64));
    }

    if (lane == 0) {
        out[b] = 0.8f * s + 0.2f * m + b4[0];
    }
}

extern "C" void kernel_launch(void* const* d_in, const int* in_sizes, int n_in,
                              void* d_out, int out_size, void* d_ws, size_t ws_size,
                              hipStream_t stream)
{
    const float* x  = (const float*)d_in[0];
    const float* W1 = (const float*)d_in[1];
    const float* b1 = (const float*)d_in[2];
    const float* W2 = (const float*)d_in[3];
    const float* b2 = (const float*)d_in[4];
    const float* W3 = (const float*)d_in[5];
    const float* b3 = (const float*)d_in[6];
    const float* W4 = (const float*)d_in[7];
    const float* b4 = (const float*)d_in[8];

    float4* ws4 = (float4*)d_ws;
    float* h1 = (float*)(ws4 + H_OFF);            // 1024x512
    float* h2 = h1 + (size_t)1024 * 512;
    float* h3 = h2 + (size_t)1024 * 512;

    transpose_all<<<640, 256, 0, stream>>>(W1, W2, W3, ws4);

    layer_k<256><<<256, NT, 0, stream>>>(x,  (const v4f*)(ws4 + WT1_OFF), b1, h1);
    layer_k<512><<<256, NT, 0, stream>>>(h1, (const v4f*)(ws4 + WT2_OFF), b2, h2);
    layer_k<512><<<256, NT, 0, stream>>>(h2, (const v4f*)(ws4 + WT3_OFF), b3, h3);
    layer4_kernel<<<256, 256, 0, stream>>>(h3, W4, b4, (float*)d_out);
}

// Round 11
// 62.055 us; speedup vs baseline: 9.9581x; 1.8954x over previous
//
#include <hip/hip_runtime.h>
#include <math.h>

// Net: 4 layers of out = 0.8*(x@W^T) + 0.2*max_i(W[o,i]*x[b,i]) + b
// B=1024, dims 256 -> 512 -> 512 -> 512 -> 1. All fp32.
//
// R11: balanced operand flow. R7's wall = h broadcast on per-CU LDS pipe
// (G=1: 4096 ds_read/CU/layer ~ 20.5us). R9 (G=4) hit the W-VMEM wall +
// spill. This is (G=2,R=2): wave = (row-pair, o-quarter), lane owns o and
// o+64 -> 2 coalesced W dwordx4 + 2 uniform ds_read_b128 per k4 per wave.
// Per CU/512-layer: LDS 10.2us, VMEM 2MB ~ 7-14us, VALU 5.1us (overlapped).
// 4-phase named-register rotation, refill-after-use, peeled tail; no
// register arrays, no runtime indexing (R6/R9 scratch lessons).

#define NT   512

typedef float v2f __attribute__((ext_vector_type(2)));
typedef float v4f __attribute__((ext_vector_type(4)));

// d_ws layout in float4 units
#define WT1_OFF 0
#define WT2_OFF 33280    // 32768 + 512 pad
#define WT3_OFF 99328    // 33280 + 65536 + 512 pad

__global__ __launch_bounds__(256) void transpose_all(
    const float* __restrict__ W1, const float* __restrict__ W2,
    const float* __restrict__ W3, float4* __restrict__ ws)
{
    const int tid = blockIdx.x * 256 + threadIdx.x;   // 0 .. 163839
    const float* W;
    float4* WT;
    int o, k4, K;
    if (tid < 32768) {                    // W1: O=512, K=256, K4=64
        W = W1; WT = ws + WT1_OFF; K = 256;
        o = tid >> 6; k4 = tid & 63;
    } else if (tid < 98304) {             // W2: O=512, K=512, K4=128
        const int idx = tid - 32768;
        W = W2; WT = ws + WT2_OFF; K = 512;
        o = idx >> 7; k4 = idx & 127;
    } else {                              // W3: O=512, K=512, K4=128
        const int idx = tid - 98304;
        W = W3; WT = ws + WT3_OFF; K = 512;
        o = idx >> 7; k4 = idx & 127;
    }
    float4 v = *(const float4*)&W[(size_t)o * K + 4 * k4];
    WT[(size_t)k4 * 512 + o] = v;
}

// One k4 (4 k-elems) for the 2x2 microtile (o_lo,o_hi) x (row0,row1).
// 24 VALU: 8 pk_mul + 8 pk_add + 8 max3.
#define STEP(WL, WH, H0, H1)                                                \
    {                                                                       \
        v4f p;                                                              \
        p = (WL) * (H0); sl0 += p;                                          \
        ml0a = fmaxf(fmaxf(ml0a, p[0]), p[1]);                              \
        ml0b = fmaxf(fmaxf(ml0b, p[2]), p[3]);                              \
        p = (WL) * (H1); sl1 += p;                                          \
        ml1a = fmaxf(fmaxf(ml1a, p[0]), p[1]);                              \
        ml1b = fmaxf(fmaxf(ml1b, p[2]), p[3]);                              \
        p = (WH) * (H0); sh0 += p;                                          \
        mh0a = fmaxf(fmaxf(mh0a, p[0]), p[1]);                              \
        mh0b = fmaxf(fmaxf(mh0b, p[2]), p[3]);                              \
        p = (WH) * (H1); sh1 += p;                                          \
        mh1a = fmaxf(fmaxf(mh1a, p[0]), p[1]);                              \
        mh1b = fmaxf(fmaxf(mh1b, p[2]), p[3]);                              \
    }

// Wave-sliced layer: this thread computes Y[2rp..2rp+1][o_lo, o_lo+64].
template<int K4>
__device__ __forceinline__ void layer_gr(
    const float (*__restrict__ hin)[512],
    float (*__restrict__ hout)[512],
    const v4f* __restrict__ WT,      // [K4][512] coalesced panels
    const float* __restrict__ bias,
    int rp, int o_lo)
{
    const v4f* wpl = WT + o_lo;
    const v4f* wph = wpl + 64;
    const v4f* h0p = (const v4f*)hin[2 * rp];
    const v4f* h1p = (const v4f*)hin[2 * rp + 1];

    v4f sl0 = (v4f)0.f, sl1 = (v4f)0.f, sh0 = (v4f)0.f, sh1 = (v4f)0.f;
    float ml0a = -INFINITY, ml0b = -INFINITY, ml1a = -INFINITY, ml1b = -INFINITY;
    float mh0a = -INFINITY, mh0b = -INFINITY, mh1a = -INFINITY, mh1b = -INFINITY;

    // 4-phase pipeline, all named registers
    v4f wl0 = wpl[0 * 512], wh0 = wph[0 * 512];
    v4f wl1 = wpl[1 * 512], wh1 = wph[1 * 512];
    v4f wl2 = wpl[2 * 512], wh2 = wph[2 * 512];
    v4f wl3 = wpl[3 * 512], wh3 = wph[3 * 512];
    v4f h00 = h0p[0], h01 = h1p[0];
    v4f h10 = h0p[1], h11 = h1p[1];
    v4f h20 = h0p[2], h21 = h1p[2];
    v4f h30 = h0p[3], h31 = h1p[3];

    #pragma unroll 1
    for (int kg = 0; kg + 4 < K4; kg += 4) {
        STEP(wl0, wh0, h00, h01);
        wl0 = wpl[(size_t)(kg + 4) * 512]; wh0 = wph[(size_t)(kg + 4) * 512];
        h00 = h0p[kg + 4]; h01 = h1p[kg + 4];
        STEP(wl1, wh1, h10, h11);
        wl1 = wpl[(size_t)(kg + 5) * 512]; wh1 = wph[(size_t)(kg + 5) * 512];
        h10 = h0p[kg + 5]; h11 = h1p[kg + 5];
        STEP(wl2, wh2, h20, h21);
        wl2 = wpl[(size_t)(kg + 6) * 512]; wh2 = wph[(size_t)(kg + 6) * 512];
        h20 = h0p[kg + 6]; h21 = h1p[kg + 6];
        STEP(wl3, wh3, h30, h31);
        wl3 = wpl[(size_t)(kg + 7) * 512]; wh3 = wph[(size_t)(kg + 7) * 512];
        h30 = h0p[kg + 7]; h31 = h1p[kg + 7];
    }
    // peeled tail (k4 = K4-4 .. K4-1), no refills
    STEP(wl0, wh0, h00, h01);
    STEP(wl1, wh1, h10, h11);
    STEP(wl2, wh2, h20, h21);
    STEP(wl3, wh3, h30, h31);

    const float blo = bias[o_lo];
    const float bhi = bias[o_lo + 64];
    {
        float s = (sl0[0] + sl0[1]) + (sl0[2] + sl0[3]);
        hout[2 * rp][o_lo] =
            fmaf(0.2f, fmaxf(ml0a, ml0b), fmaf(0.8f, s, blo));
    }
    {
        float s = (sl1[0] + sl1[1]) + (sl1[2] + sl1[3]);
        hout[2 * rp + 1][o_lo] =
            fmaf(0.2f, fmaxf(ml1a, ml1b), fmaf(0.8f, s, blo));
    }
    {
        float s = (sh0[0] + sh0[1]) + (sh0[2] + sh0[3]);
        hout[2 * rp][o_lo + 64] =
            fmaf(0.2f, fmaxf(mh0a, mh0b), fmaf(0.8f, s, bhi));
    }
    {
        float s = (sh1[0] + sh1[1]) + (sh1[2] + sh1[3]);
        hout[2 * rp + 1][o_lo + 64] =
            fmaf(0.2f, fmaxf(mh1a, mh1b), fmaf(0.8f, s, bhi));
    }
}

__global__ __launch_bounds__(NT) void net_fused(
    const float* __restrict__ x,
    const v4f* __restrict__ WT1, const float* __restrict__ b1,
    const v4f* __restrict__ WT2, const float* __restrict__ b2,
    const v4f* __restrict__ WT3, const float* __restrict__ b3,
    const float* __restrict__ W4, const float* __restrict__ b4,
    float* __restrict__ out)
{
    __shared__ __align__(16) float ha[4][512];
    __shared__ __align__(16) float hb[4][512];
    __shared__ float red_s[8][4];
    __shared__ float red_m[8][4];

    const int t = threadIdx.x;
    const int row0 = blockIdx.x * 4;

    // stage x rows (4 x 256) into ha: one float2 per thread
    {
        const int r = t >> 7;
        const int c = (t & 127) * 2;
        float2 v = *(const float2*)&x[(size_t)(row0 + r) * 256 + c];
        ha[r][c]     = v.x;
        ha[r][c + 1] = v.y;
    }
    __syncthreads();

    const int wave = t >> 6;
    const int lane = t & 63;
    const int rp   = wave & 1;                 // row-pair
    const int o_lo = (wave >> 1) * 128 + lane; // this lane's low o

    layer_gr<64> (ha, hb, WT1, b1, rp, o_lo);   // x  -> h1
    __syncthreads();
    layer_gr<128>(hb, ha, WT2, b2, rp, o_lo);   // h1 -> h2
    __syncthreads();
    layer_gr<128>(ha, hb, WT3, b3, rp, o_lo);   // h2 -> h3
    __syncthreads();

    // ---- layer 4: O=1 ----
    const float w4 = W4[t];
    float ps0, ps1, ps2, ps3, pm0, pm1, pm2, pm3;
    {
        float p0 = w4 * hb[0][t]; ps0 = p0; pm0 = p0;
        float p1 = w4 * hb[1][t]; ps1 = p1; pm1 = p1;
        float p2 = w4 * hb[2][t]; ps2 = p2; pm2 = p2;
        float p3 = w4 * hb[3][t]; ps3 = p3; pm3 = p3;
    }
    #pragma unroll
    for (int off = 32; off; off >>= 1) {
        ps0 += __shfl_xor(ps0, off, 64);
        pm0 = fmaxf(pm0, __shfl_xor(pm0, off, 64));
        ps1 += __shfl_xor(ps1, off, 64);
        pm1 = fmaxf(pm1, __shfl_xor(pm1, off, 64));
        ps2 += __shfl_xor(ps2, off, 64);
        pm2 = fmaxf(pm2, __shfl_xor(pm2, off, 64));
        ps3 += __shfl_xor(ps3, off, 64);
        pm3 = fmaxf(pm3, __shfl_xor(pm3, off, 64));
    }
    if (lane == 0) {
        red_s[wave][0] = ps0; red_m[wave][0] = pm0;
        red_s[wave][1] = ps1; red_m[wave][1] = pm1;
        red_s[wave][2] = ps2; red_m[wave][2] = pm2;
        red_s[wave][3] = ps3; red_m[wave][3] = pm3;
    }
    __syncthreads();

    if (t < 4) {
        float s = red_s[0][t];
        float m = red_m[0][t];
        #pragma unroll
        for (int w = 1; w < 8; ++w) {
            s += red_s[w][t];
            m = fmaxf(m, red_m[w][t]);
        }
        out[row0 + t] = fmaf(0.2f, m, fmaf(0.8f, s, b4[0]));
    }
}

extern "C" void kernel_launch(void* const* d_in, const int* in_sizes, int n_in,
                              void* d_out, int out_size, void* d_ws, size_t ws_size,
                              hipStream_t stream)
{
    const float* x  = (const float*)d_in[0];
    const float* W1 = (const float*)d_in[1];
    const float* b1 = (const float*)d_in[2];
    const float* W2 = (const float*)d_in[3];
    const float* b2 = (const float*)d_in[4];
    const float* W3 = (const float*)d_in[5];
    const float* b3 = (const float*)d_in[6];
    const float* W4 = (const float*)d_in[7];
    const float* b4 = (const float*)d_in[8];

    float4* ws4 = (float4*)d_ws;

    transpose_all<<<640, 256, 0, stream>>>(W1, W2, W3, ws4);

    net_fused<<<256, NT, 0, stream>>>(
        x,
        (const v4f*)(ws4 + WT1_OFF), b1,
        (const v4f*)(ws4 + WT2_OFF), b2,
        (const v4f*)(ws4 + WT3_OFF), b3,
        W4, b4,
        (float*)d_out);
}